// Round 3
// baseline (390.249 us; speedup 1.0000x reference)
//
#include <hip/hip_runtime.h>
#include <hip/hip_bf16.h>
#include <hip/hip_fp16.h>
#include <type_traits>

typedef _Float16 f16;
typedef __attribute__((ext_vector_type(8))) _Float16 f16x8;
typedef __attribute__((ext_vector_type(4))) float floatx4;

#define B_ 4
#define T_ 2048
#define D_ 1024

// ws layout (bytes); total need = 106,954,752
#define XB_OFF   0ul          // f16 x: 16 MB ; reused as Vt after QKV GEMM
#define WB_OFF   16777216ul   // f16 W concat (3072x1024): 6 MB
#define QKV_OFF  23068672ul   // f16 qkv (8192x3072): 48 MB
#define S_OFF    73400320ul   // f16 S (4x2048x2048): 32 MB
#define VT_OFF   0ul          // f16 Vt (4x1024x2048): 16 MB (overwrites xb)

// async global->LDS, 16B per lane; lds dest = wave-uniform base + lane*16
#define ASYNC16(gp, lp) \
    __builtin_amdgcn_global_load_lds((const __attribute__((address_space(1))) unsigned int*)(gp), \
                                     (__attribute__((address_space(3))) unsigned int*)(lp), 16, 0, 0)

// ---------------- cast fp32 -> fp16 (x and the three W's) ----------------
__global__ __launch_bounds__(256) void cast_all(
    const float* __restrict__ x, const float* __restrict__ wq,
    const float* __restrict__ wk, const float* __restrict__ wv,
    f16* __restrict__ xb, f16* __restrict__ wb)
{
    long i = (long)blockIdx.x * 256 + threadIdx.x;   // group-of-4 index
    const float4* src; f16* dst;
    if (i < 2097152L)            { src = (const float4*)x;  dst = xb; }
    else if (i < 2359296L)       { i -= 2097152L; src = (const float4*)wq; dst = wb; }
    else if (i < 2621440L)       { i -= 2359296L; src = (const float4*)wk; dst = wb + 1048576; }
    else                         { i -= 2621440L; src = (const float4*)wv; dst = wb + 2097152; }
    float4 v = src[i];
    union { f16 h[4]; uint2 u; } o;
    o.h[0] = (f16)v.x; o.h[1] = (f16)v.y; o.h[2] = (f16)v.z; o.h[3] = (f16)v.w;
    ((uint2*)dst)[i] = o.u;
}

// ---------------- NT GEMM: C[m,n] = alpha * sum_k A[m,k]*B[n,k] ----------------
// Block 128 x BN, BK=64. 4 waves 2x2; wave tile 64 x BN/2; 16x16x32 MFMA.
// LDS layout [kslab][row][8] (kslab = k>>3): DMA-contiguous per 64-row slab,
// fragment b128 reads land 2 lanes/bank (conflict-free, m136).
template <typename CT, int BN>
__global__ __launch_bounds__(256) void gemm_nt(
    const f16* __restrict__ A, int lda, long sA,
    const f16* __restrict__ B, int ldb, long sB,
    CT* __restrict__ C, int ldc, long sC,
    int K, float alpha)
{
    __shared__ f16 As[8 * 128 * 8];     // 16 KB
    __shared__ f16 Bs[8 * BN * 8];      // 16 or 8 KB

    const int tid = threadIdx.x;
    const int m0 = blockIdx.y * 128;
    const int n0 = blockIdx.x * BN;
    const int bz = blockIdx.z;
    A += (long)bz * sA + (long)m0 * lda;
    B += (long)bz * sB + (long)n0 * ldb;
    C += (long)bz * sC;

    const int w  = tid >> 6;
    const int l  = tid & 63;
    const int wm = (w >> 1) * 64;
    const int wn = (w & 1) * (BN / 2);
    const int lr = l & 15;    // m (A) / n (B) within 16-tile
    const int kg = l >> 4;    // k-group: k = kg*8 .. kg*8+7

    constexpr int NI = BN / 32;         // 4 or 2 col-tiles per wave
    floatx4 acc[4][NI] = {};

    const f16* Al = A + (long)l * lda;  // lane-private row base
    const f16* Bl = B + (long)l * ldb;

    for (int k0 = 0; k0 < K; k0 += 64) {
        // A: 16 wave-DMA chunks (kslab 0..7 x rowhalf 0..1), 4 per wave
        #pragma unroll
        for (int c = 0; c < 4; c++) {
            int ks = 2 * w + (c >> 1);
            int rh = c & 1;
            ASYNC16(Al + k0 + ks * 8 + rh * 64 * lda, &As[ks * 1024 + rh * 512]);
        }
        if constexpr (BN == 128) {
            #pragma unroll
            for (int c = 0; c < 4; c++) {
                int ks = 2 * w + (c >> 1);
                int rh = c & 1;
                ASYNC16(Bl + k0 + ks * 8 + rh * 64 * ldb, &Bs[ks * 1024 + rh * 512]);
            }
        } else {
            #pragma unroll
            for (int c = 0; c < 2; c++) {
                int ks = 2 * w + c;
                ASYNC16(Bl + k0 + ks * 8, &Bs[ks * 512]);
            }
        }
        __syncthreads();   // DMA drain -> tiles visible

        #pragma unroll
        for (int s = 0; s < 2; s++) {
            f16x8 af[4], bf[NI];
            #pragma unroll
            for (int mi = 0; mi < 4; mi++)
                af[mi] = *(const f16x8*)&As[(s * 4 + kg) * 1024 + (wm + mi * 16 + lr) * 8];
            #pragma unroll
            for (int ni = 0; ni < NI; ni++)
                bf[ni] = *(const f16x8*)&Bs[(s * 4 + kg) * (BN * 8) + (wn + ni * 16 + lr) * 8];
            #pragma unroll
            for (int mi = 0; mi < 4; mi++)
                #pragma unroll
                for (int ni = 0; ni < NI; ni++)
                    acc[mi][ni] = __builtin_amdgcn_mfma_f32_16x16x32_f16(af[mi], bf[ni], acc[mi][ni], 0, 0, 0);
        }
        __syncthreads();   // readers done before next DMA overwrites
    }

    // epilogue: C/D layout: col = lane&15, row = (lane>>4)*4 + reg
    #pragma unroll
    for (int mi = 0; mi < 4; mi++) {
        #pragma unroll
        for (int ni = 0; ni < NI; ni++) {
            #pragma unroll
            for (int r = 0; r < 4; r++) {
                int row = m0 + wm + mi * 16 + kg * 4 + r;
                int col = n0 + wn + ni * 16 + lr;
                float v = acc[mi][ni][r] * alpha;
                if constexpr (std::is_same<CT, float>::value)
                    C[(long)row * ldc + col] = v;
                else
                    C[(long)row * ldc + col] = (f16)v;
            }
        }
    }
}

// ---------------- transpose V (within qkv) -> Vt[b][d][j] ----------------
__global__ __launch_bounds__(256) void transpose_v(const f16* __restrict__ qkv, f16* __restrict__ vt)
{
    __shared__ f16 tile[32][33];
    int b  = blockIdx.z;
    int j0 = blockIdx.x * 32;
    int d0 = blockIdx.y * 32;
    int tx = threadIdx.x & 31;
    int ty = threadIdx.x >> 5;   // 0..7
    #pragma unroll
    for (int i = 0; i < 4; i++) {
        int j = j0 + ty + i * 8;
        tile[ty + i * 8][tx] = qkv[((long)b * T_ + j) * 3072 + 2048 + d0 + tx];
    }
    __syncthreads();
    #pragma unroll
    for (int i = 0; i < 4; i++) {
        int d = d0 + ty + i * 8;
        vt[((long)b * D_ + d) * T_ + j0 + tx] = tile[tx][ty + i * 8];
    }
}

// ---------------- row softmax: one wave per row, no barriers ----------------
__global__ __launch_bounds__(256) void softmax_rows(f16* __restrict__ S)
{
    long row = (long)blockIdx.x * 4 + (threadIdx.x >> 6);
    int l = threadIdx.x & 63;
    uint4* p4 = (uint4*)(S + row * 2048);
    union U { uint4 u; f16 h[8]; } d[4];
    float v[32];
    float mx = -1e30f;
    #pragma unroll
    for (int i = 0; i < 4; i++) {
        d[i].u = p4[i * 64 + l];
        #pragma unroll
        for (int j = 0; j < 8; j++) { v[i * 8 + j] = (float)d[i].h[j]; mx = fmaxf(mx, v[i * 8 + j]); }
    }
    #pragma unroll
    for (int off = 32; off; off >>= 1) mx = fmaxf(mx, __shfl_xor(mx, off, 64));
    float s = 0.f;
    #pragma unroll
    for (int i = 0; i < 32; i++) { v[i] = __expf(v[i] - mx); s += v[i]; }
    #pragma unroll
    for (int off = 32; off; off >>= 1) s += __shfl_xor(s, off, 64);
    float inv = 1.f / s;
    #pragma unroll
    for (int i = 0; i < 4; i++) {
        #pragma unroll
        for (int j = 0; j < 8; j++) d[i].h[j] = (f16)(v[i * 8 + j] * inv);
        p4[i * 64 + l] = d[i].u;
    }
}

// ---------------- launch ----------------
extern "C" void kernel_launch(void* const* d_in, const int* in_sizes, int n_in,
                              void* d_out, int out_size, void* d_ws, size_t ws_size,
                              hipStream_t stream)
{
    const float* x  = (const float*)d_in[0];
    const float* wq = (const float*)d_in[1];
    const float* wk = (const float*)d_in[2];
    const float* wv = (const float*)d_in[3];
    float* out = (float*)d_out;
    char* ws = (char*)d_ws;
    f16* xb  = (f16*)(ws + XB_OFF);
    f16* wb  = (f16*)(ws + WB_OFF);
    f16* qkv = (f16*)(ws + QKV_OFF);
    f16* s   = (f16*)(ws + S_OFF);
    f16* vt  = (f16*)(ws + VT_OFF);

    // 1) cast x, Wq, Wk, Wv to fp16 (Wb = [Wq;Wk;Wv] as 3072x1024)
    cast_all<<<11264, 256, 0, stream>>>(x, wq, wk, wv, xb, wb);

    // 2) QKV = xb @ Wb^T : M=8192, N=3072, K=1024, fp16 out
    gemm_nt<f16, 128><<<dim3(24, 64, 1), 256, 0, stream>>>(
        xb, 1024, 0L, wb, 1024, 0L, qkv, 3072, 0L, 1024, 1.0f);

    // 3) Vt[b][d][j] = V[b][j][d]
    transpose_v<<<dim3(64, 32, 4), 256, 0, stream>>>(qkv, vt);

    // 4) S = (1/32) * Q @ K^T per batch : M=N=2048, K=1024
    gemm_nt<f16, 128><<<dim3(16, 16, 4), 256, 0, stream>>>(
        qkv,        3072, (long)T_ * 3072,
        qkv + 1024, 3072, (long)T_ * 3072,
        s,          2048, (long)T_ * 2048, 1024, 0.03125f);

    // 5) softmax rows, in place (1 wave/row, 4 rows/block)
    softmax_rows<<<2048, 256, 0, stream>>>(s);

    // 6) O = P @ Vt^T per batch : M=2048, N=1024, K=2048, fp32 out -> d_out
    gemm_nt<float, 64><<<dim3(16, 16, 4), 256, 0, stream>>>(
        s,  2048, (long)T_ * 2048,
        vt, 2048, (long)D_ * 2048,
        out, 1024, (long)T_ * 1024, 2048, 1.0f);
}

// Round 4
// 297.160 us; speedup vs baseline: 1.3133x; 1.3133x over previous
//
#include <hip/hip_runtime.h>
#include <hip/hip_bf16.h>
#include <hip/hip_fp16.h>
#include <type_traits>

typedef _Float16 f16;
typedef __attribute__((ext_vector_type(8))) _Float16 f16x8;
typedef __attribute__((ext_vector_type(4))) float floatx4;

#define B_ 4
#define T_ 2048
#define D_ 1024

// ws layout (bytes); total need = 106,954,752
#define XB_OFF   0ul          // f16 x: 16 MB ; reused as Vt after QKV GEMM
#define WB_OFF   16777216ul   // f16 W concat (3072x1024): 6 MB
#define QKV_OFF  23068672ul   // f16 qkv (8192x3072): 48 MB
#define S_OFF    73400320ul   // f16 S (4x2048x2048): 32 MB
#define VT_OFF   0ul          // f16 Vt (4x1024x2048): 16 MB (overwrites xb)

// async global->LDS, 16B per lane; lds dest = wave-uniform base + lane*16
#define ASYNC16(gp, lp) \
    __builtin_amdgcn_global_load_lds((const __attribute__((address_space(1))) unsigned int*)(gp), \
                                     (__attribute__((address_space(3))) unsigned int*)(lp), 16, 0, 0)

// ---------------- cast fp32 -> fp16 (x and the three W's) ----------------
__global__ __launch_bounds__(256) void cast_all(
    const float* __restrict__ x, const float* __restrict__ wq,
    const float* __restrict__ wk, const float* __restrict__ wv,
    f16* __restrict__ xb, f16* __restrict__ wb)
{
    long i = (long)blockIdx.x * 256 + threadIdx.x;   // group-of-4 index
    const float4* src; f16* dst;
    if (i < 2097152L)            { src = (const float4*)x;  dst = xb; }
    else if (i < 2359296L)       { i -= 2097152L; src = (const float4*)wq; dst = wb; }
    else if (i < 2621440L)       { i -= 2359296L; src = (const float4*)wk; dst = wb + 1048576; }
    else                         { i -= 2621440L; src = (const float4*)wv; dst = wb + 2097152; }
    float4 v = src[i];
    union { f16 h[4]; uint2 u; } o;
    o.h[0] = (f16)v.x; o.h[1] = (f16)v.y; o.h[2] = (f16)v.z; o.h[3] = (f16)v.w;
    ((uint2*)dst)[i] = o.u;
}

// ---------------- NT GEMM: C[m,n] = alpha * sum_k A[m,k]*B[n,k] ----------------
// Block 128 x BN, BK=32, double-buffered LDS, single barrier per iter.
// 4 waves 2x2; wave tile 64 x BN/2; 16x16x32 MFMA.
// LDS row-major [row][32] with XOR swizzle WITHIN each row's 64B segment:
//   LDS slab s of row m holds global slab s^(m&3). DMA stays 64B-coalesced
//   (same address set as unswizzled, permuted within the line); fragment
//   reads use kx = kg^(lr&3) -> 8 lanes/bank-quad at >=256B spacing
//   (the pattern R3 measured at ZERO conflicts).
template <typename CT, int BN>
__global__ __launch_bounds__(256) void gemm_nt(
    const f16* __restrict__ A, int lda, long sA,
    const f16* __restrict__ B, int ldb, long sB,
    CT* __restrict__ C, int ldc, long sC,
    int K, float alpha)
{
    __shared__ f16 As[2][128 * 32];    // 16 KB
    __shared__ f16 Bs[2][BN * 32];     // 16 or 8 KB

    const int tid = threadIdx.x;
    const int m0 = blockIdx.y * 128;
    const int n0 = blockIdx.x * BN;
    const int bz = blockIdx.z;
    A += (long)bz * sA;
    B += (long)bz * sB;
    C += (long)bz * sC;

    const int w  = tid >> 6;
    const int l  = tid & 63;
    const int wm = (w >> 1) * 64;
    const int wn = (w & 1) * (BN / 2);
    const int lr = l & 15;          // m (A) / n (B) within 16-tile
    const int kg = l >> 4;          // k-group 0..3 (k = kg*8..kg*8+7)
    const int kx = kg ^ (lr & 3);   // swizzled LDS slab for fragment reads

    constexpr int NI = BN / 32;
    floatx4 acc[4][NI] = {};

    // staging: lane covers row srow; fetches global slab gsl (XOR swizzle)
    const int srow = tid >> 2;                 // 0..63
    const int gsl  = (tid & 3) ^ (srow & 3);   // (srow+64)&3 == srow&3, so same for both A chunks
    const long ldaL = lda, ldbL = ldb;
    const f16* Aptr = A + (long)(m0 + srow) * ldaL + gsl * 8;
    const f16* Bptr = B + (long)(n0 + srow) * ldbL + gsl * 8;

    auto stage = [&](int b, int kk) {
        ASYNC16(Aptr + kk,              &As[b][w * 512]);
        ASYNC16(Aptr + kk + 64 * ldaL,  &As[b][w * 512 + 2048]);
        ASYNC16(Bptr + kk,              &Bs[b][w * 512]);
        if constexpr (BN == 128)
            ASYNC16(Bptr + kk + 64 * ldbL, &Bs[b][w * 512 + 2048]);
    };

    stage(0, 0);
    __syncthreads();

    for (int k0 = 0; k0 < K; k0 += 32) {
        const int cur = (k0 >> 5) & 1;
        if (k0 + 32 < K) stage(cur ^ 1, k0 + 32);   // prefetch overlaps compute below

        f16x8 af[4], bf[NI];
        #pragma unroll
        for (int mi = 0; mi < 4; mi++)
            af[mi] = *(const f16x8*)&As[cur][(wm + mi * 16 + lr) * 32 + kx * 8];
        #pragma unroll
        for (int ni = 0; ni < NI; ni++)
            bf[ni] = *(const f16x8*)&Bs[cur][(wn + ni * 16 + lr) * 32 + kx * 8];
        #pragma unroll
        for (int mi = 0; mi < 4; mi++)
            #pragma unroll
            for (int ni = 0; ni < NI; ni++)
                acc[mi][ni] = __builtin_amdgcn_mfma_f32_16x16x32_f16(af[mi], bf[ni], acc[mi][ni], 0, 0, 0);

        __syncthreads();   // drains prefetch DMA (visible next iter) + read/write fence
    }

    // epilogue: C/D layout: col = lane&15, row = (lane>>4)*4 + reg
    #pragma unroll
    for (int mi = 0; mi < 4; mi++) {
        #pragma unroll
        for (int ni = 0; ni < NI; ni++) {
            #pragma unroll
            for (int r = 0; r < 4; r++) {
                int row = m0 + wm + mi * 16 + kg * 4 + r;
                int col = n0 + wn + ni * 16 + lr;
                float v = acc[mi][ni][r] * alpha;
                if constexpr (std::is_same<CT, float>::value)
                    C[(long)row * ldc + col] = v;
                else
                    C[(long)row * ldc + col] = (f16)v;
            }
        }
    }
}

// ---------------- transpose V (within qkv) -> Vt[b][d][j] ----------------
__global__ __launch_bounds__(256) void transpose_v(const f16* __restrict__ qkv, f16* __restrict__ vt)
{
    __shared__ f16 tile[32][33];
    int b  = blockIdx.z;
    int j0 = blockIdx.x * 32;
    int d0 = blockIdx.y * 32;
    int tx = threadIdx.x & 31;
    int ty = threadIdx.x >> 5;   // 0..7
    #pragma unroll
    for (int i = 0; i < 4; i++) {
        int j = j0 + ty + i * 8;
        tile[ty + i * 8][tx] = qkv[((long)b * T_ + j) * 3072 + 2048 + d0 + tx];
    }
    __syncthreads();
    #pragma unroll
    for (int i = 0; i < 4; i++) {
        int d = d0 + ty + i * 8;
        vt[((long)b * D_ + d) * T_ + j0 + tx] = tile[tx][ty + i * 8];
    }
}

// ---------------- row softmax: one wave per row, no barriers ----------------
__global__ __launch_bounds__(256) void softmax_rows(f16* __restrict__ S)
{
    long row = (long)blockIdx.x * 4 + (threadIdx.x >> 6);
    int l = threadIdx.x & 63;
    uint4* p4 = (uint4*)(S + row * 2048);
    union U { uint4 u; f16 h[8]; } d[4];
    float v[32];
    float mx = -1e30f;
    #pragma unroll
    for (int i = 0; i < 4; i++) {
        d[i].u = p4[i * 64 + l];
        #pragma unroll
        for (int j = 0; j < 8; j++) { v[i * 8 + j] = (float)d[i].h[j]; mx = fmaxf(mx, v[i * 8 + j]); }
    }
    #pragma unroll
    for (int off = 32; off; off >>= 1) mx = fmaxf(mx, __shfl_xor(mx, off, 64));
    float s = 0.f;
    #pragma unroll
    for (int i = 0; i < 32; i++) { v[i] = __expf(v[i] - mx); s += v[i]; }
    #pragma unroll
    for (int off = 32; off; off >>= 1) s += __shfl_xor(s, off, 64);
    float inv = 1.f / s;
    #pragma unroll
    for (int i = 0; i < 4; i++) {
        #pragma unroll
        for (int j = 0; j < 8; j++) d[i].h[j] = (f16)(v[i * 8 + j] * inv);
        p4[i * 64 + l] = d[i].u;
    }
}

// ---------------- launch ----------------
extern "C" void kernel_launch(void* const* d_in, const int* in_sizes, int n_in,
                              void* d_out, int out_size, void* d_ws, size_t ws_size,
                              hipStream_t stream)
{
    const float* x  = (const float*)d_in[0];
    const float* wq = (const float*)d_in[1];
    const float* wk = (const float*)d_in[2];
    const float* wv = (const float*)d_in[3];
    float* out = (float*)d_out;
    char* ws = (char*)d_ws;
    f16* xb  = (f16*)(ws + XB_OFF);
    f16* wb  = (f16*)(ws + WB_OFF);
    f16* qkv = (f16*)(ws + QKV_OFF);
    f16* s   = (f16*)(ws + S_OFF);
    f16* vt  = (f16*)(ws + VT_OFF);

    // 1) cast x, Wq, Wk, Wv to fp16 (Wb = [Wq;Wk;Wv] as 3072x1024)
    cast_all<<<11264, 256, 0, stream>>>(x, wq, wk, wv, xb, wb);

    // 2) QKV = xb @ Wb^T : M=8192, N=3072, K=1024, fp16 out
    gemm_nt<f16, 128><<<dim3(24, 64, 1), 256, 0, stream>>>(
        xb, 1024, 0L, wb, 1024, 0L, qkv, 3072, 0L, 1024, 1.0f);

    // 3) Vt[b][d][j] = V[b][j][d]
    transpose_v<<<dim3(64, 32, 4), 256, 0, stream>>>(qkv, vt);

    // 4) S = (1/32) * Q @ K^T per batch : M=N=2048, K=1024
    gemm_nt<f16, 128><<<dim3(16, 16, 4), 256, 0, stream>>>(
        qkv,        3072, (long)T_ * 3072,
        qkv + 1024, 3072, (long)T_ * 3072,
        s,          2048, (long)T_ * 2048, 1024, 0.03125f);

    // 5) softmax rows, in place (1 wave/row, 4 rows/block)
    softmax_rows<<<2048, 256, 0, stream>>>(s);

    // 6) O = P @ Vt^T per batch : M=2048, N=1024, K=2048, fp32 out -> d_out
    gemm_nt<float, 64><<<dim3(16, 16, 4), 256, 0, stream>>>(
        s,  2048, (long)T_ * 2048,
        vt, 2048, (long)D_ * 2048,
        out, 1024, (long)T_ * 1024, 2048, 1.0f);
}

// Round 5
// 292.794 us; speedup vs baseline: 1.3328x; 1.0149x over previous
//
#include <hip/hip_runtime.h>
#include <hip/hip_bf16.h>
#include <hip/hip_fp16.h>
#include <type_traits>

typedef _Float16 f16;
typedef __attribute__((ext_vector_type(8))) _Float16 f16x8;
typedef __attribute__((ext_vector_type(4))) float floatx4;

#define B_ 4
#define T_ 2048
#define D_ 1024

// ws layout (bytes); total need = 106,954,752
#define XB_OFF   0ul          // f16 x: 16 MB ; reused as Vt after QKV GEMM
#define WB_OFF   16777216ul   // f16 W concat (3072x1024): 6 MB
#define QKV_OFF  23068672ul   // f16 qkv (8192x3072): 48 MB
#define S_OFF    73400320ul   // f16 S (4x2048x2048): 32 MB
#define VT_OFF   0ul          // f16 Vt (4x1024x2048): 16 MB (overwrites xb)

// async global->LDS, 16B per lane; lds dest = wave-uniform base + lane*16
#define ASYNC16(gp, lp) \
    __builtin_amdgcn_global_load_lds((const __attribute__((address_space(1))) unsigned int*)(gp), \
                                     (__attribute__((address_space(3))) unsigned int*)(lp), 16, 0, 0)

// ---------------- cast fp32 -> fp16 (x and the three W's) ----------------
__global__ __launch_bounds__(256) void cast_all(
    const float* __restrict__ x, const float* __restrict__ wq,
    const float* __restrict__ wk, const float* __restrict__ wv,
    f16* __restrict__ xb, f16* __restrict__ wb)
{
    long i = (long)blockIdx.x * 256 + threadIdx.x;   // group-of-4 index
    const float4* src; f16* dst;
    if (i < 2097152L)            { src = (const float4*)x;  dst = xb; }
    else if (i < 2359296L)       { i -= 2097152L; src = (const float4*)wq; dst = wb; }
    else if (i < 2621440L)       { i -= 2359296L; src = (const float4*)wk; dst = wb + 1048576; }
    else                         { i -= 2621440L; src = (const float4*)wv; dst = wb + 2097152; }
    float4 v = src[i];
    union { f16 h[4]; uint2 u; } o;
    o.h[0] = (f16)v.x; o.h[1] = (f16)v.y; o.h[2] = (f16)v.z; o.h[3] = (f16)v.w;
    ((uint2*)dst)[i] = o.u;
}

// ---------------- NT GEMM: C[m,n] = alpha * sum_k A[m,k]*B[n,k] ----------------
// Block 128 x BN, BK=32, double-buffered LDS, single barrier per iter.
// 4 waves 2x2; wave tile 64 x BN/2; 16x16x32 MFMA.
// LDS [row][32] with PERIOD-8 XOR swizzle inside each row's 64B segment:
//   LDS slab s of row r holds global slab s ^ ((r>>1)&3).
//   DMA: lane tid stages LDS (row=tid>>2, s=tid&3), fetches global slab
//        gsl = (tid&3)^((tid>>3)&3)  -> still one 64B line per 4-lane group.
//   Read: lane needs global slab kg -> LDS slab kx = kg^((lr>>1)&3).
//   Bank-quad per 8-lane phase enumerates {0,4,1,5,2,6,3,7} -> conflict-free.
template <typename CT, int BN>
__global__ __launch_bounds__(256) void gemm_nt(
    const f16* __restrict__ A, int lda, long sA,
    const f16* __restrict__ B, int ldb, long sB,
    CT* __restrict__ C, int ldc, long sC,
    int K, float alpha)
{
    __shared__ f16 As[2][128 * 32];    // 16 KB
    __shared__ f16 Bs[2][BN * 32];     // 16 KB (BN=128)

    const int tid = threadIdx.x;
    const int m0 = blockIdx.y * 128;
    const int n0 = blockIdx.x * BN;
    const int bz = blockIdx.z;
    A += (long)bz * sA;
    B += (long)bz * sB;
    C += (long)bz * sC;

    const int w  = tid >> 6;
    const int l  = tid & 63;
    const int wm = (w >> 1) * 64;
    const int wn = (w & 1) * (BN / 2);
    const int lr = l & 15;                 // m (A) / n (B) within 16-tile
    const int kg = l >> 4;                 // k-group 0..3 (k = kg*8..kg*8+7)
    const int kx = kg ^ ((lr >> 1) & 3);   // period-8 swizzled LDS slab

    constexpr int NI = BN / 32;
    floatx4 acc[4][NI] = {};

    // staging: lane covers row srow, LDS slab tid&3; fetches global slab gsl
    const int srow = tid >> 2;                            // 0..63
    const int gsl  = (tid & 3) ^ ((tid >> 3) & 3);        // rows r and r+64 share (r>>1)&3
    const long ldaL = lda, ldbL = ldb;
    const f16* Aptr = A + (long)(m0 + srow) * ldaL + gsl * 8;
    const f16* Bptr = B + (long)(n0 + srow) * ldbL + gsl * 8;

    auto stage = [&](int b, int kk) {
        ASYNC16(Aptr + kk,              &As[b][w * 512]);
        ASYNC16(Aptr + kk + 64 * ldaL,  &As[b][w * 512 + 2048]);
        ASYNC16(Bptr + kk,              &Bs[b][w * 512]);
        if constexpr (BN == 128)
            ASYNC16(Bptr + kk + 64 * ldbL, &Bs[b][w * 512 + 2048]);
    };

    stage(0, 0);
    __syncthreads();

    for (int k0 = 0; k0 < K; k0 += 32) {
        const int cur = (k0 >> 5) & 1;
        if (k0 + 32 < K) stage(cur ^ 1, k0 + 32);   // prefetch overlaps compute below

        f16x8 af[4], bf[NI];
        #pragma unroll
        for (int mi = 0; mi < 4; mi++)
            af[mi] = *(const f16x8*)&As[cur][(wm + mi * 16 + lr) * 32 + kx * 8];
        #pragma unroll
        for (int ni = 0; ni < NI; ni++)
            bf[ni] = *(const f16x8*)&Bs[cur][(wn + ni * 16 + lr) * 32 + kx * 8];
        #pragma unroll
        for (int mi = 0; mi < 4; mi++)
            #pragma unroll
            for (int ni = 0; ni < NI; ni++)
                acc[mi][ni] = __builtin_amdgcn_mfma_f32_16x16x32_f16(af[mi], bf[ni], acc[mi][ni], 0, 0, 0);

        __syncthreads();   // drains prefetch DMA (visible next iter) + read/write fence
    }

    // epilogue: C/D layout: col = lane&15, row = (lane>>4)*4 + reg
    #pragma unroll
    for (int mi = 0; mi < 4; mi++) {
        #pragma unroll
        for (int ni = 0; ni < NI; ni++) {
            #pragma unroll
            for (int r = 0; r < 4; r++) {
                int row = m0 + wm + mi * 16 + kg * 4 + r;
                int col = n0 + wn + ni * 16 + lr;
                float v = acc[mi][ni][r] * alpha;
                if constexpr (std::is_same<CT, float>::value)
                    C[(long)row * ldc + col] = v;
                else
                    C[(long)row * ldc + col] = (f16)v;
            }
        }
    }
}

// ---------------- transpose V (within qkv) -> Vt[b][d][j] ----------------
__global__ __launch_bounds__(256) void transpose_v(const f16* __restrict__ qkv, f16* __restrict__ vt)
{
    __shared__ f16 tile[32][33];
    int b  = blockIdx.z;
    int j0 = blockIdx.x * 32;
    int d0 = blockIdx.y * 32;
    int tx = threadIdx.x & 31;
    int ty = threadIdx.x >> 5;   // 0..7
    #pragma unroll
    for (int i = 0; i < 4; i++) {
        int j = j0 + ty + i * 8;
        tile[ty + i * 8][tx] = qkv[((long)b * T_ + j) * 3072 + 2048 + d0 + tx];
    }
    __syncthreads();
    #pragma unroll
    for (int i = 0; i < 4; i++) {
        int d = d0 + ty + i * 8;
        vt[((long)b * D_ + d) * T_ + j0 + tx] = tile[tx][ty + i * 8];
    }
}

// ---------------- row softmax: one wave per row, no barriers ----------------
__global__ __launch_bounds__(256) void softmax_rows(f16* __restrict__ S)
{
    long row = (long)blockIdx.x * 4 + (threadIdx.x >> 6);
    int l = threadIdx.x & 63;
    uint4* p4 = (uint4*)(S + row * 2048);
    union U { uint4 u; f16 h[8]; } d[4];
    float v[32];
    float mx = -1e30f;
    #pragma unroll
    for (int i = 0; i < 4; i++) {
        d[i].u = p4[i * 64 + l];
        #pragma unroll
        for (int j = 0; j < 8; j++) { v[i * 8 + j] = (float)d[i].h[j]; mx = fmaxf(mx, v[i * 8 + j]); }
    }
    #pragma unroll
    for (int off = 32; off; off >>= 1) mx = fmaxf(mx, __shfl_xor(mx, off, 64));
    float s = 0.f;
    #pragma unroll
    for (int i = 0; i < 32; i++) { v[i] = __expf(v[i] - mx); s += v[i]; }
    #pragma unroll
    for (int off = 32; off; off >>= 1) s += __shfl_xor(s, off, 64);
    float inv = 1.f / s;
    #pragma unroll
    for (int i = 0; i < 4; i++) {
        #pragma unroll
        for (int j = 0; j < 8; j++) d[i].h[j] = (f16)(v[i * 8 + j] * inv);
        p4[i * 64 + l] = d[i].u;
    }
}

// ---------------- launch ----------------
extern "C" void kernel_launch(void* const* d_in, const int* in_sizes, int n_in,
                              void* d_out, int out_size, void* d_ws, size_t ws_size,
                              hipStream_t stream)
{
    const float* x  = (const float*)d_in[0];
    const float* wq = (const float*)d_in[1];
    const float* wk = (const float*)d_in[2];
    const float* wv = (const float*)d_in[3];
    float* out = (float*)d_out;
    char* ws = (char*)d_ws;
    f16* xb  = (f16*)(ws + XB_OFF);
    f16* wb  = (f16*)(ws + WB_OFF);
    f16* qkv = (f16*)(ws + QKV_OFF);
    f16* s   = (f16*)(ws + S_OFF);
    f16* vt  = (f16*)(ws + VT_OFF);

    // 1) cast x, Wq, Wk, Wv to fp16 (Wb = [Wq;Wk;Wv] as 3072x1024)
    cast_all<<<11264, 256, 0, stream>>>(x, wq, wk, wv, xb, wb);

    // 2) QKV = xb @ Wb^T : M=8192, N=3072, K=1024, fp16 out
    gemm_nt<f16, 128><<<dim3(24, 64, 1), 256, 0, stream>>>(
        xb, 1024, 0L, wb, 1024, 0L, qkv, 3072, 0L, 1024, 1.0f);

    // 3) Vt[b][d][j] = V[b][j][d]
    transpose_v<<<dim3(64, 32, 4), 256, 0, stream>>>(qkv, vt);

    // 4) S = (1/32) * Q @ K^T per batch : M=N=2048, K=1024
    gemm_nt<f16, 128><<<dim3(16, 16, 4), 256, 0, stream>>>(
        qkv,        3072, (long)T_ * 3072,
        qkv + 1024, 3072, (long)T_ * 3072,
        s,          2048, (long)T_ * 2048, 1024, 0.03125f);

    // 5) softmax rows, in place (1 wave/row, 4 rows/block)
    softmax_rows<<<2048, 256, 0, stream>>>(s);

    // 6) O = P @ Vt^T per batch : M=2048, N=1024, K=2048, fp32 out -> d_out
    gemm_nt<float, 128><<<dim3(8, 16, 4), 256, 0, stream>>>(
        s,  2048, (long)T_ * 2048,
        vt, 2048, (long)D_ * 2048,
        out, 1024, (long)T_ * 1024, 2048, 1.0f);
}

// Round 6
// 278.257 us; speedup vs baseline: 1.4025x; 1.0522x over previous
//
#include <hip/hip_runtime.h>
#include <hip/hip_bf16.h>
#include <hip/hip_fp16.h>
#include <type_traits>

typedef _Float16 f16;
typedef __attribute__((ext_vector_type(8))) _Float16 f16x8;
typedef __attribute__((ext_vector_type(4))) float floatx4;

#define B_ 4
#define T_ 2048
#define D_ 1024

// ws layout (bytes); total need = 106,954,752
#define XB_OFF   0ul          // f16 x: 16 MB ; reused as Vt after QKV GEMM
#define WB_OFF   16777216ul   // f16 W concat (3072x1024): 6 MB
#define QKV_OFF  23068672ul   // f16 qkv (8192x3072): 48 MB
#define S_OFF    73400320ul   // f16 S (4x2048x2048): 32 MB
#define VT_OFF   0ul          // f16 Vt (4x1024x2048): 16 MB (overwrites xb)

// async global->LDS, 16B per lane; lds dest = wave-uniform base + lane*16
#define ASYNC16(gp, lp) \
    __builtin_amdgcn_global_load_lds((const __attribute__((address_space(1))) unsigned int*)(gp), \
                                     (__attribute__((address_space(3))) unsigned int*)(lp), 16, 0, 0)

// ---------------- cast fp32 -> fp16 (x and the three W's) ----------------
__global__ __launch_bounds__(256) void cast_all(
    const float* __restrict__ x, const float* __restrict__ wq,
    const float* __restrict__ wk, const float* __restrict__ wv,
    f16* __restrict__ xb, f16* __restrict__ wb)
{
    long i = (long)blockIdx.x * 256 + threadIdx.x;   // group-of-4 index
    const float4* src; f16* dst;
    if (i < 2097152L)            { src = (const float4*)x;  dst = xb; }
    else if (i < 2359296L)       { i -= 2097152L; src = (const float4*)wq; dst = wb; }
    else if (i < 2621440L)       { i -= 2359296L; src = (const float4*)wk; dst = wb + 1048576; }
    else                         { i -= 2621440L; src = (const float4*)wv; dst = wb + 2097152; }
    float4 v = src[i];
    union { f16 h[4]; uint2 u; } o;
    o.h[0] = (f16)v.x; o.h[1] = (f16)v.y; o.h[2] = (f16)v.z; o.h[3] = (f16)v.w;
    ((uint2*)dst)[i] = o.u;
}

// ---------------- NT GEMM: C[m,n] = alpha * sum_k A[m,k]*B[n,k] ----------------
// Block 128 x BN, BK=32, double-buffered LDS, single barrier per iter.
// 4 waves arranged 2 (rows) x 2 (cols); wave tile 64 x WN; 16x16x32 MFMA.
// WN=128 -> 12 b128 reads feed 32 MFMAs per wave-iter (0.375 reads/MFMA);
// WN=64  -> classic 8 reads / 16 MFMA.
// LDS [row][32] with PERIOD-8 XOR swizzle inside each row's 64B segment:
//   LDS slab s of row r holds global slab s ^ ((r>>1)&3).
//   DMA: lane tid stages LDS (row=tid>>2, s=tid&3), fetches global slab
//        gsl = (tid&3)^((tid>>3)&3)  -> one 64B line per 4-lane group.
//   Read: lane needs global slab kg -> LDS slab kx = kg^((lr>>1)&3).
//   Bank-quad per 8-lane phase enumerates {0,4,1,5,2,6,3,7} -> conflict-free
//   (measured: SQ_LDS_BANK_CONFLICT == 0, R5).
template <typename CT, int BN, int WN>
__global__ __launch_bounds__(256, 2) void gemm_nt(
    const f16* __restrict__ A, int lda, long sA,
    const f16* __restrict__ B, int ldb, long sB,
    CT* __restrict__ C, int ldc, long sC,
    int K, float alpha)
{
    __shared__ f16 As[2][128 * 32];    // 16 KB
    __shared__ f16 Bs[2][BN * 32];     // 16 KB (BN=256: 32 KB)

    const int tid = threadIdx.x;
    const int m0 = blockIdx.y * 128;
    const int n0 = blockIdx.x * BN;
    const int bz = blockIdx.z;
    A += (long)bz * sA;
    B += (long)bz * sB;
    C += (long)bz * sC;

    const int w  = tid >> 6;
    const int l  = tid & 63;
    const int wm = (w >> 1) * 64;
    const int wn = (w & 1) * WN;
    const int lr = l & 15;                 // m (A) / n (B) within 16-tile
    const int kg = l >> 4;                 // k-group 0..3 (k = kg*8..kg*8+7)
    const int kx = kg ^ ((lr >> 1) & 3);   // period-8 swizzled LDS slab

    constexpr int NI = WN / 16;
    floatx4 acc[4][NI] = {};

    // staging: lane covers row srow, LDS slab tid&3; fetches global slab gsl
    const int srow = tid >> 2;                            // 0..63
    const int gsl  = (tid & 3) ^ ((tid >> 3) & 3);        // rows r, r+64, r+128.. share (r>>1)&3
    const long ldaL = lda, ldbL = ldb;
    const f16* Aptr = A + (long)(m0 + srow) * ldaL + gsl * 8;
    const f16* Bptr = B + (long)(n0 + srow) * ldbL + gsl * 8;

    auto stage = [&](int b, int kk) {
        #pragma unroll
        for (int rh = 0; rh < 2; rh++)
            ASYNC16(Aptr + kk + rh * 64 * ldaL, &As[b][rh * 2048 + w * 512]);
        #pragma unroll
        for (int rh = 0; rh < BN / 64; rh++)
            ASYNC16(Bptr + kk + rh * 64 * ldbL, &Bs[b][rh * 2048 + w * 512]);
    };

    stage(0, 0);
    __syncthreads();

    for (int k0 = 0; k0 < K; k0 += 32) {
        const int cur = (k0 >> 5) & 1;
        if (k0 + 32 < K) stage(cur ^ 1, k0 + 32);   // prefetch overlaps compute below

        f16x8 af[4], bf[NI];
        #pragma unroll
        for (int mi = 0; mi < 4; mi++)
            af[mi] = *(const f16x8*)&As[cur][(wm + mi * 16 + lr) * 32 + kx * 8];
        #pragma unroll
        for (int ni = 0; ni < NI; ni++)
            bf[ni] = *(const f16x8*)&Bs[cur][(wn + ni * 16 + lr) * 32 + kx * 8];
        #pragma unroll
        for (int mi = 0; mi < 4; mi++)
            #pragma unroll
            for (int ni = 0; ni < NI; ni++)
                acc[mi][ni] = __builtin_amdgcn_mfma_f32_16x16x32_f16(af[mi], bf[ni], acc[mi][ni], 0, 0, 0);

        __syncthreads();   // drains prefetch DMA (visible next iter) + read/write fence
    }

    // epilogue: C/D layout: col = lane&15, row = (lane>>4)*4 + reg
    #pragma unroll
    for (int mi = 0; mi < 4; mi++) {
        #pragma unroll
        for (int ni = 0; ni < NI; ni++) {
            #pragma unroll
            for (int r = 0; r < 4; r++) {
                int row = m0 + wm + mi * 16 + kg * 4 + r;
                int col = n0 + wn + ni * 16 + lr;
                float v = acc[mi][ni][r] * alpha;
                if constexpr (std::is_same<CT, float>::value)
                    C[(long)row * ldc + col] = v;
                else
                    C[(long)row * ldc + col] = (f16)v;
            }
        }
    }
}

// ---------------- transpose V (within qkv) -> Vt[b][d][j] ----------------
__global__ __launch_bounds__(256) void transpose_v(const f16* __restrict__ qkv, f16* __restrict__ vt)
{
    __shared__ f16 tile[32][33];
    int b  = blockIdx.z;
    int j0 = blockIdx.x * 32;
    int d0 = blockIdx.y * 32;
    int tx = threadIdx.x & 31;
    int ty = threadIdx.x >> 5;   // 0..7
    #pragma unroll
    for (int i = 0; i < 4; i++) {
        int j = j0 + ty + i * 8;
        tile[ty + i * 8][tx] = qkv[((long)b * T_ + j) * 3072 + 2048 + d0 + tx];
    }
    __syncthreads();
    #pragma unroll
    for (int i = 0; i < 4; i++) {
        int d = d0 + ty + i * 8;
        vt[((long)b * D_ + d) * T_ + j0 + tx] = tile[tx][ty + i * 8];
    }
}

// ---------------- row softmax: one wave per row, no barriers ----------------
__global__ __launch_bounds__(256) void softmax_rows(f16* __restrict__ S)
{
    long row = (long)blockIdx.x * 4 + (threadIdx.x >> 6);
    int l = threadIdx.x & 63;
    uint4* p4 = (uint4*)(S + row * 2048);
    union U { uint4 u; f16 h[8]; } d[4];
    float v[32];
    float mx = -1e30f;
    #pragma unroll
    for (int i = 0; i < 4; i++) {
        d[i].u = p4[i * 64 + l];
        #pragma unroll
        for (int j = 0; j < 8; j++) { v[i * 8 + j] = (float)d[i].h[j]; mx = fmaxf(mx, v[i * 8 + j]); }
    }
    #pragma unroll
    for (int off = 32; off; off >>= 1) mx = fmaxf(mx, __shfl_xor(mx, off, 64));
    float s = 0.f;
    #pragma unroll
    for (int i = 0; i < 32; i++) { v[i] = __expf(v[i] - mx); s += v[i]; }
    #pragma unroll
    for (int off = 32; off; off >>= 1) s += __shfl_xor(s, off, 64);
    float inv = 1.f / s;
    #pragma unroll
    for (int i = 0; i < 4; i++) {
        #pragma unroll
        for (int j = 0; j < 8; j++) d[i].h[j] = (f16)(v[i * 8 + j] * inv);
        p4[i * 64 + l] = d[i].u;
    }
}

// ---------------- launch ----------------
extern "C" void kernel_launch(void* const* d_in, const int* in_sizes, int n_in,
                              void* d_out, int out_size, void* d_ws, size_t ws_size,
                              hipStream_t stream)
{
    const float* x  = (const float*)d_in[0];
    const float* wq = (const float*)d_in[1];
    const float* wk = (const float*)d_in[2];
    const float* wv = (const float*)d_in[3];
    float* out = (float*)d_out;
    char* ws = (char*)d_ws;
    f16* xb  = (f16*)(ws + XB_OFF);
    f16* wb  = (f16*)(ws + WB_OFF);
    f16* qkv = (f16*)(ws + QKV_OFF);
    f16* s   = (f16*)(ws + S_OFF);
    f16* vt  = (f16*)(ws + VT_OFF);

    // 1) cast x, Wq, Wk, Wv to fp16 (Wb = [Wq;Wk;Wv] as 3072x1024)
    cast_all<<<11264, 256, 0, stream>>>(x, wq, wk, wv, xb, wb);

    // 2) QKV = xb @ Wb^T : M=8192, N=3072, K=1024, fp16 out (block 128x256, wave 64x128)
    gemm_nt<f16, 256, 128><<<dim3(12, 64, 1), 256, 0, stream>>>(
        xb, 1024, 0L, wb, 1024, 0L, qkv, 3072, 0L, 1024, 1.0f);

    // 3) Vt[b][d][j] = V[b][j][d]
    transpose_v<<<dim3(64, 32, 4), 256, 0, stream>>>(qkv, vt);

    // 4) S = (1/32) * Q @ K^T per batch : M=N=2048, K=1024 (block 128x256, wave 64x128)
    gemm_nt<f16, 256, 128><<<dim3(8, 16, 4), 256, 0, stream>>>(
        qkv,        3072, (long)T_ * 3072,
        qkv + 1024, 3072, (long)T_ * 3072,
        s,          2048, (long)T_ * 2048, 1024, 0.03125f);

    // 5) softmax rows, in place (1 wave/row, 4 rows/block)
    softmax_rows<<<2048, 256, 0, stream>>>(s);

    // 6) O = P @ Vt^T per batch : M=2048, N=1024, K=2048, fp32 out -> d_out
    //    (block 128x128, wave 64x64 — N too small for 256-wide tiles at >=2 blocks/CU)
    gemm_nt<float, 128, 64><<<dim3(8, 16, 4), 256, 0, stream>>>(
        s,  2048, (long)T_ * 2048,
        vt, 2048, (long)D_ * 2048,
        out, 1024, (long)T_ * 1024, 2048, 1.0f);
}